// Round 7
// baseline (178.026 us; speedup 1.0000x reference)
//
#include <hip/hip_runtime.h>
#include <math.h>

#define NN   2048
#define BB   16

// ws layout (float offsets)
#define WS_X0   0
#define WS_QT   65536
#define WS_KT   131072
#define WS_VT   196608
#define WS_PART 262144   // [32 slot][4 h][4 kslice][12]: o[8], ssum, pad
#define WS_GI   268800   // [16 edge][96]

__device__ __forceinline__ float sigmoidf_(float x) { return 1.0f / (1.0f + __expf(-x)); }
__device__ __forceinline__ float tanhf_(float x) {
    float ex = __expf(2.0f * x);
    return 1.0f - 2.0f / (ex + 1.0f);
}
__device__ __forceinline__ float dot4_(float4 a, float4 b) {
    return a.x*b.x + a.y*b.y + a.z*b.z + a.w*b.w;
}

// ---------------------------------------------------------------------------
// K1: 256 blocks. All: x0 = nf@Wemb^T+b ; qkv = x0@Wqkv^T+b (head-major).
//     blocks 0..15: message path for edge bx -> gi[bx][96].
//     blocks 16..79: memory -> out[16..] bulk copy.   (unchanged from R6)
// ---------------------------------------------------------------------------
__global__ __launch_bounds__(256) void k1_embed_qkv_msg(
    const float* __restrict__ nf, const float* __restrict__ Wemb, const float* __restrict__ bemb,
    const float* __restrict__ Wqkv, const float* __restrict__ bqkv,
    const float* __restrict__ mem, const int* __restrict__ src, const int* __restrict__ dst,
    const float* __restrict__ ef,
    const float* __restrict__ Wm1, const float* __restrict__ bm1,
    const float* __restrict__ Wm2, const float* __restrict__ bm2,
    const float* __restrict__ Wih, const float* __restrict__ bih,
    float* __restrict__ ws, float* __restrict__ out)
{
    __shared__ float We_s[32 * 130];
    __shared__ float nf_s[8 * 130];
    __shared__ float x0_s[8 * 33];
    __shared__ float Wq_s[96 * 33];
    __shared__ __align__(16) float Wm1_s[2144];
    __shared__ float Wm2_s[32 * 33];
    __shared__ float Wih_s[96 * 33];
    __shared__ float min_s[67];
    __shared__ float mr_s[32];
    __shared__ float msg_s[32];

    const int t = threadIdx.x, bx = blockIdx.x;
    const bool domsg = (bx < 16);

    float4 rA[4], rB[3], rC;
    #pragma unroll
    for (int k = 0; k < 4; ++k) rA[k] = ((const float4*)Wemb)[t + 256 * k];
    #pragma unroll
    for (int k = 0; k < 3; ++k) rB[k] = ((const float4*)Wqkv)[t + 256 * k];
    rC = ((const float4*)nf)[bx * 256 + t];

    float4 rm1[3], rm2v, rih[3];
    float rminv = 0.f;
    if (domsg) {
        #pragma unroll
        for (int k = 0; k < 3; ++k) {
            int idx = t + 256 * k;
            rm1[k] = (idx < 536) ? ((const float4*)Wm1)[idx] : make_float4(0,0,0,0);
        }
        rm2v = ((const float4*)Wm2)[t];
        #pragma unroll
        for (int k = 0; k < 3; ++k) rih[k] = ((const float4*)Wih)[t + 256 * k];
        if (t < 67) {
            const int e = bx;
            rminv = (t < 32) ? mem[src[e] * 32 + t]
                  : (t < 64) ? mem[dst[e] * 32 + (t - 32)]
                             : ef[e * 3 + (t - 64)];
        }
    }

    if (bx >= 16 && bx < 80) {
        int g = (bx - 16) * 256 + t;
        ((float4*)(out + 16))[g] = ((const float4*)mem)[g];
    }

    #pragma unroll
    for (int k = 0; k < 4; ++k) {
        int idx = t + 256 * k;
        int r = idx >> 5, c = (idx & 31) * 4;
        We_s[r * 130 + c] = rA[k].x; We_s[r * 130 + c + 1] = rA[k].y;
        We_s[r * 130 + c + 2] = rA[k].z; We_s[r * 130 + c + 3] = rA[k].w;
    }
    #pragma unroll
    for (int k = 0; k < 3; ++k) {
        int idx = t + 256 * k;
        int r = idx >> 3, c = (idx & 7) * 4;
        Wq_s[r * 33 + c] = rB[k].x; Wq_s[r * 33 + c + 1] = rB[k].y;
        Wq_s[r * 33 + c + 2] = rB[k].z; Wq_s[r * 33 + c + 3] = rB[k].w;
    }
    {
        int r = t >> 5, c = (t & 31) * 4;
        nf_s[r * 130 + c] = rC.x; nf_s[r * 130 + c + 1] = rC.y;
        nf_s[r * 130 + c + 2] = rC.z; nf_s[r * 130 + c + 3] = rC.w;
    }
    if (domsg) {
        #pragma unroll
        for (int k = 0; k < 3; ++k) {
            int idx = t + 256 * k;
            if (idx < 536) ((float4*)Wm1_s)[idx] = rm1[k];
        }
        { int r = t >> 3, c = (t & 7) * 4;
          Wm2_s[r * 33 + c] = rm2v.x; Wm2_s[r * 33 + c + 1] = rm2v.y;
          Wm2_s[r * 33 + c + 2] = rm2v.z; Wm2_s[r * 33 + c + 3] = rm2v.w; }
        #pragma unroll
        for (int k = 0; k < 3; ++k) {
            int idx = t + 256 * k;
            int r = idx >> 3, c = (idx & 7) * 4;
            Wih_s[r * 33 + c] = rih[k].x; Wih_s[r * 33 + c + 1] = rih[k].y;
            Wih_s[r * 33 + c + 2] = rih[k].z; Wih_s[r * 33 + c + 3] = rih[k].w;
        }
        if (t < 67) min_s[t] = rminv;
    }
    __syncthreads();

    const int j = t >> 5, o = t & 31;
    const int n = bx * 8 + j;

    float acc = bemb[o];
    {
        const float2* Wr = (const float2*)&We_s[o * 130];
        const float2* Nr = (const float2*)&nf_s[j * 130];
        float sx = 0.f, sy = 0.f;
        #pragma unroll 16
        for (int i = 0; i < 64; ++i) {
            float2 w = Wr[i], x = Nr[i];
            sx += w.x * x.x; sy += w.y * x.y;
        }
        acc += sx + sy;
    }
    x0_s[j * 33 + o] = acc;
    ws[WS_X0 + n * 32 + o] = acc;
    if (domsg && t < 32) {
        float a1 = bm1[t];
        for (int i = 0; i < 67; ++i) a1 += Wm1_s[t * 67 + i] * min_s[i];
        mr_s[t] = fmaxf(a1, 0.f);
    }
    __syncthreads();

    #pragma unroll
    for (int c = 0; c < 3; ++c) {
        int oo = c * 32 + o;
        float a2 = bqkv[oo];
        #pragma unroll 8
        for (int i = 0; i < 32; ++i) a2 += Wq_s[oo * 33 + i] * x0_s[j * 33 + i];
        int h = o >> 3, d = o & 7;
        float* base = ws + (c == 0 ? WS_QT : (c == 1 ? WS_KT : WS_VT));
        base[h * 16384 + n * 8 + d] = a2;  // [h][n][d]
    }
    if (domsg && t < 32) {
        float a2 = bm2[t];
        #pragma unroll 8
        for (int i = 0; i < 32; ++i) a2 += Wm2_s[t * 33 + i] * mr_s[i];
        msg_s[t] = a2;
    }
    __syncthreads();

    if (domsg && t < 96) {
        float a3 = bih[t];
        #pragma unroll 8
        for (int i = 0; i < 32; ++i) a3 += Wih_s[t * 33 + i] * msg_s[i];
        ws[WS_GI + bx * 96 + t] = a3;  // [e][96]
    }
}

// ---------------------------------------------------------------------------
// K2: attention for the 32 gathered query slots (unchanged from R6).
// ---------------------------------------------------------------------------
__global__ __launch_bounds__(256) void k2_attn(
    const int* __restrict__ src, const int* __restrict__ dst,
    float* __restrict__ ws)
{
    const int t = threadIdx.x, bx = blockIdx.x;
    const int s  = bx >> 2;
    const int ks = bx & 3;
    const int h  = t >> 6;
    const int l  = t & 63;

    const int e = s >> 1;
    const int n = (s & 1) ? dst[e] : src[e];

    const float* qg = ws + WS_QT + h * 16384 + n * 8;
    const float4 qa  = *(const float4*)qg;
    const float4 qb4 = *(const float4*)(qg + 4);
    const float* kbase = ws + WS_KT + h * 16384;
    const float* vbase = ws + WS_VT + h * 16384;

    float4 oa = make_float4(0.f, 0.f, 0.f, 0.f);
    float4 ob = make_float4(0.f, 0.f, 0.f, 0.f);
    float ssum = 0.f;
    const float scale = 0.35355339059327373f;  // 1/sqrt(8)

    #pragma unroll
    for (int i = 0; i < 8; ++i) {
        const int key = ks * 512 + i * 64 + l;
        const float4 ka = *(const float4*)(kbase + key * 8);
        const float4 kb = *(const float4*)(kbase + key * 8 + 4);
        const float sc = (dot4_(qa, ka) + dot4_(qb4, kb)) * scale;
        const float p = __expf(sc);
        ssum += p;
        const float4 va = *(const float4*)(vbase + key * 8);
        const float4 vb = *(const float4*)(vbase + key * 8 + 4);
        oa.x += p * va.x; oa.y += p * va.y; oa.z += p * va.z; oa.w += p * va.w;
        ob.x += p * vb.x; ob.y += p * vb.y; ob.z += p * vb.z; ob.w += p * vb.w;
    }

    #pragma unroll
    for (int m = 1; m <= 32; m <<= 1) {
        ssum += __shfl_xor(ssum, m);
        oa.x += __shfl_xor(oa.x, m); oa.y += __shfl_xor(oa.y, m);
        oa.z += __shfl_xor(oa.z, m); oa.w += __shfl_xor(oa.w, m);
        ob.x += __shfl_xor(ob.x, m); ob.y += __shfl_xor(ob.y, m);
        ob.z += __shfl_xor(ob.z, m); ob.w += __shfl_xor(ob.w, m);
    }
    if (l == 0) {
        float* p = ws + WS_PART + ((s * 4 + h) * 4 + ks) * 12;
        *(float4*)p       = oa;
        *(float4*)(p + 4) = ob;
        p[8] = ssum;
    }
}

// ---------------------------------------------------------------------------
// K34: one block, 256 threads. CODE-SIZE-MINIMIZED:
//  - per-lane weight rows live in registers (8-16 float4 global loads/phase);
//    no LDS weight staging at all.
//  - all slot-group loops are rolled (#pragma unroll 1); only innermost
//    dot-product chains unrolled. FP accumulation order identical to R6.
//  - gi read directly from ws in the GRU (zero reuse -> no staging).
// ---------------------------------------------------------------------------
__global__ __launch_bounds__(256, 1) void k34_post_scan(
    const int* __restrict__ src, const int* __restrict__ dst,
    const float* __restrict__ mem,
    const float* __restrict__ Wo, const float* __restrict__ bo,
    const float* __restrict__ g1, const float* __restrict__ be1,
    const float* __restrict__ Wf1, const float* __restrict__ bf1,
    const float* __restrict__ Wf2, const float* __restrict__ bf2,
    const float* __restrict__ g2, const float* __restrict__ be2,
    const float* __restrict__ Wscn, const float* __restrict__ bscn,
    const float* __restrict__ gscn, const float* __restrict__ bescn,
    const float* __restrict__ Whh, const float* __restrict__ bhh,
    const float* __restrict__ We1, const float* __restrict__ be1e,
    const float* __restrict__ We2, const float* __restrict__ be2e,
    const float* __restrict__ We3, const float* __restrict__ be3,
    float* __restrict__ ws, float* __restrict__ out)
{
    __shared__ float arow[32 * 33];   // attn rows; later edge-cat (16x33)
    __shared__ float x1s[32 * 33];
    __shared__ float fs[32 * 65];     // x0 stash -> FFN hidden -> h1/h2
    __shared__ __align__(16) float slots[32 * 36];
    __shared__ int nid_s[32], prev_s[32], round_s[32], last_s[32];
    __shared__ int list_s[32], cnt_s, maxr_s;

    const int t = threadIdx.x;
    const int j0 = t >> 5, o = t & 31;
    const int l = t & 63, w = t >> 6;
    const bool lowhalf = (l < 32);

    // ---- GRU weights into registers at entry (latency hides under phases) ----
    float4 w1[8], w2[8], w3[8];
    const int r2 = lowhalf ? l + 64 : l - 32;
    const int r3 = l + 32;
    #pragma unroll
    for (int c = 0; c < 8; ++c) {
        w1[c] = ((const float4*)Whh)[l * 8 + c];
        w2[c] = ((const float4*)Whh)[r2 * 8 + c];
        w3[c] = ((const float4*)Whh)[r3 * 8 + c];
    }
    const float b1 = bhh[l], b2 = bhh[r2], b3 = bhh[r3];

    if (t < 32) nid_s[t] = (t & 1) ? dst[t >> 1] : src[t >> 1];

    // ---- combine attn partials -> arow ; stash x0 -> fs ----
    #pragma unroll 1
    for (int si = 0; si < 4; ++si) {
        const int jj = si * 8 + j0;
        const int ej = jj >> 1;
        const int n = (jj & 1) ? dst[ej] : src[ej];
        const int h = o >> 3, d = o & 7;
        float num = 0.f, den = 0.f;
        #pragma unroll
        for (int ks = 0; ks < 4; ++ks) {
            const float* p = ws + WS_PART + ((jj * 4 + h) * 4 + ks) * 12;
            num += p[d];
            den += p[8];
        }
        arow[jj * 33 + o] = num / den;
        fs[jj * 65 + o] = ws[WS_X0 + n * 32 + o];
    }
    __syncthreads();

    // bookkeeping (wave 0) + slots init (all waves)
    if (t < 32) {
        const int me = nid_s[t];
        int pv = -1, rd = 0;
        for (int j2 = 0; j2 < t; ++j2) if (nid_s[j2] == me) { pv = j2; ++rd; }
        prev_s[t] = pv; round_s[t] = rd;
        int isl = 1;
        for (int j2 = t + 1; j2 < 32; ++j2) if (nid_s[j2] == me) { isl = 0; break; }
        last_s[t] = isl;
        int mr = rd;
        #pragma unroll
        for (int m = 16; m >= 1; m >>= 1) mr = max(mr, __shfl_xor(mr, m, 32));
        if (t == 0) maxr_s = mr;
    }
    #pragma unroll
    for (int k = 0; k < 4; ++k) {
        int j2 = j0 + 8 * k;
        slots[j2 * 36 + o] = mem[nid_s[j2] * 32 + o];
    }

    // ---- A1: Wo GEMM + residual + LN1 -> x1s ----
    {
        float4 wv[8];
        #pragma unroll
        for (int c = 0; c < 8; ++c) wv[c] = ((const float4*)(Wo + o * 32))[c];
        const float bv = bo[o], gv = g1[o], bev = be1[o];
        #pragma unroll 1
        for (int si = 0; si < 4; ++si) {
            const int jj = si * 8 + j0;
            float a = bv;
            #pragma unroll
            for (int c = 0; c < 8; ++c) {
                a = fmaf(wv[c].x, arow[jj * 33 + 4 * c],     a);
                a = fmaf(wv[c].y, arow[jj * 33 + 4 * c + 1], a);
                a = fmaf(wv[c].z, arow[jj * 33 + 4 * c + 2], a);
                a = fmaf(wv[c].w, arow[jj * 33 + 4 * c + 3], a);
            }
            float t1 = fs[jj * 65 + o] + a;
            float mu = t1;
            #pragma unroll
            for (int m = 16; m >= 1; m >>= 1) mu += __shfl_xor(mu, m, 32);
            mu *= (1.f / 32.f);
            float dv = t1 - mu;
            float var = dv * dv;
            #pragma unroll
            for (int m = 16; m >= 1; m >>= 1) var += __shfl_xor(var, m, 32);
            var *= (1.f / 32.f);
            x1s[jj * 33 + o] = dv * rsqrtf(var + 1e-5f) * gv + bev;
        }
    }
    __syncthreads();

    // ---- A2: FFN1 + gelu -> fs (rows o and o+32) ----
    {
        float4 wa[8], wb[8];
        #pragma unroll
        for (int c = 0; c < 8; ++c) {
            wa[c] = ((const float4*)(Wf1 + o * 32))[c];
            wb[c] = ((const float4*)(Wf1 + (o + 32) * 32))[c];
        }
        const float ba = bf1[o], bb = bf1[o + 32];
        #pragma unroll 1
        for (int si = 0; si < 4; ++si) {
            const int jj = si * 8 + j0;
            float f0 = ba, f1 = bb;
            #pragma unroll
            for (int c = 0; c < 8; ++c) {
                const float xa = x1s[jj * 33 + 4 * c];
                const float xb = x1s[jj * 33 + 4 * c + 1];
                const float xc = x1s[jj * 33 + 4 * c + 2];
                const float xd = x1s[jj * 33 + 4 * c + 3];
                f0 = fmaf(wa[c].x, xa, f0); f0 = fmaf(wa[c].y, xb, f0);
                f0 = fmaf(wa[c].z, xc, f0); f0 = fmaf(wa[c].w, xd, f0);
                f1 = fmaf(wb[c].x, xa, f1); f1 = fmaf(wb[c].y, xb, f1);
                f1 = fmaf(wb[c].z, xc, f1); f1 = fmaf(wb[c].w, xd, f1);
            }
            fs[jj * 65 + o]      = 0.5f * f0 * (1.f + erff(f0 * 0.70710678118654752f));
            fs[jj * 65 + 32 + o] = 0.5f * f1 * (1.f + erff(f1 * 0.70710678118654752f));
        }
    }
    __syncthreads();

    // ---- A3: FFN2 + residual + LN2 -> x1s ----
    {
        float4 wv[16];
        #pragma unroll
        for (int c = 0; c < 16; ++c) wv[c] = ((const float4*)(Wf2 + o * 64))[c];
        const float bv = bf2[o], gv = g2[o], bev = be2[o];
        #pragma unroll 1
        for (int si = 0; si < 4; ++si) {
            const int jj = si * 8 + j0;
            float f2 = bv;
            #pragma unroll
            for (int c = 0; c < 16; ++c) {
                f2 = fmaf(wv[c].x, fs[jj * 65 + 4 * c],     f2);
                f2 = fmaf(wv[c].y, fs[jj * 65 + 4 * c + 1], f2);
                f2 = fmaf(wv[c].z, fs[jj * 65 + 4 * c + 2], f2);
                f2 = fmaf(wv[c].w, fs[jj * 65 + 4 * c + 3], f2);
            }
            float t2 = x1s[jj * 33 + o] + f2;
            float mu2 = t2;
            #pragma unroll
            for (int m = 16; m >= 1; m >>= 1) mu2 += __shfl_xor(mu2, m, 32);
            mu2 *= (1.f / 32.f);
            float dv2 = t2 - mu2;
            float var2 = dv2 * dv2;
            #pragma unroll
            for (int m = 16; m >= 1; m >>= 1) var2 += __shfl_xor(var2, m, 32);
            var2 *= (1.f / 32.f);
            x1s[jj * 33 + o] = dv2 * rsqrtf(var2 + 1e-5f) * gv + bev;
        }
    }
    __syncthreads();

    // ---- A4: SCN + LN(16) + relu -> edge-cat layout in arow ----
    if (o < 16) {
        float4 wv[8];
        #pragma unroll
        for (int c = 0; c < 8; ++c) wv[c] = ((const float4*)(Wscn + o * 32))[c];
        const float bv = bscn[o], gv = gscn[o], bev = bescn[o];
        #pragma unroll 1
        for (int si = 0; si < 4; ++si) {
            const int jj = si * 8 + j0;
            float sc = bv;
            #pragma unroll
            for (int c = 0; c < 8; ++c) {
                sc = fmaf(wv[c].x, x1s[jj * 33 + 4 * c],     sc);
                sc = fmaf(wv[c].y, x1s[jj * 33 + 4 * c + 1], sc);
                sc = fmaf(wv[c].z, x1s[jj * 33 + 4 * c + 2], sc);
                sc = fmaf(wv[c].w, x1s[jj * 33 + 4 * c + 3], sc);
            }
            float m16 = sc;
            #pragma unroll
            for (int m = 8; m >= 1; m >>= 1) m16 += __shfl_xor(m16, m, 16);
            m16 *= (1.f / 16.f);
            float d16 = sc - m16;
            float v16 = d16 * d16;
            #pragma unroll
            for (int m = 8; m >= 1; m >>= 1) v16 += __shfl_xor(v16, m, 16);
            v16 *= (1.f / 16.f);
            float sv = d16 * rsqrtf(v16 + 1e-5f) * gv + bev;
            arow[(jj >> 1) * 33 + (jj & 1) * 16 + o] = fmaxf(sv, 0.f);
        }
    }
    __syncthreads();

    // ---- A6: h1 = relu(cat @ We1^T) ----
    {
        float4 wv[8];
        #pragma unroll
        for (int c = 0; c < 8; ++c) wv[c] = ((const float4*)(We1 + o * 32))[c];
        const float bv = be1e[o];
        #pragma unroll 1
        for (int k = 0; k < 2; ++k) {
            int e = j0 + 8 * k;
            float acc = bv;
            #pragma unroll
            for (int c = 0; c < 8; ++c) {
                acc = fmaf(wv[c].x, arow[e * 33 + 4 * c],     acc);
                acc = fmaf(wv[c].y, arow[e * 33 + 4 * c + 1], acc);
                acc = fmaf(wv[c].z, arow[e * 33 + 4 * c + 2], acc);
                acc = fmaf(wv[c].w, arow[e * 33 + 4 * c + 3], acc);
            }
            fs[e * 33 + o] = fmaxf(acc, 0.f);
        }
    }
    __syncthreads();

    // ---- A7: h2 = relu(h1 @ We2^T) ----
    {
        const int e = t >> 4, o2 = t & 15;
        float4 wv[8];
        #pragma unroll
        for (int c = 0; c < 8; ++c) wv[c] = ((const float4*)(We2 + o2 * 32))[c];
        float acc = be2e[o2];
        #pragma unroll
        for (int c = 0; c < 8; ++c) {
            acc = fmaf(wv[c].x, fs[e * 33 + 4 * c],     acc);
            acc = fmaf(wv[c].y, fs[e * 33 + 4 * c + 1], acc);
            acc = fmaf(wv[c].z, fs[e * 33 + 4 * c + 2], acc);
            acc = fmaf(wv[c].w, fs[e * 33 + 4 * c + 3], acc);
        }
        __syncthreads();
        fs[600 + e * 17 + o2] = fmaxf(acc, 0.f);
    }
    __syncthreads();

    // ---- A8: logits ----
    if (t < 16) {
        float4 w3a = ((const float4*)We3)[0], w3b = ((const float4*)We3)[1];
        float4 w3c = ((const float4*)We3)[2], w3d = ((const float4*)We3)[3];
        float acc = be3[0];
        acc = fmaf(w3a.x, fs[600 + t * 17 + 0], acc);  acc = fmaf(w3a.y, fs[600 + t * 17 + 1], acc);
        acc = fmaf(w3a.z, fs[600 + t * 17 + 2], acc);  acc = fmaf(w3a.w, fs[600 + t * 17 + 3], acc);
        acc = fmaf(w3b.x, fs[600 + t * 17 + 4], acc);  acc = fmaf(w3b.y, fs[600 + t * 17 + 5], acc);
        acc = fmaf(w3b.z, fs[600 + t * 17 + 6], acc);  acc = fmaf(w3b.w, fs[600 + t * 17 + 7], acc);
        acc = fmaf(w3c.x, fs[600 + t * 17 + 8], acc);  acc = fmaf(w3c.y, fs[600 + t * 17 + 9], acc);
        acc = fmaf(w3c.z, fs[600 + t * 17 + 10], acc); acc = fmaf(w3c.w, fs[600 + t * 17 + 11], acc);
        acc = fmaf(w3d.x, fs[600 + t * 17 + 12], acc); acc = fmaf(w3d.y, fs[600 + t * 17 + 13], acc);
        acc = fmaf(w3d.z, fs[600 + t * 17 + 14], acc); acc = fmaf(w3d.w, fs[600 + t * 17 + 15], acc);
        out[t] = acc;
    }

    // ---- PARALLEL GRU scan over dependency rounds ----
    const int maxr = maxr_s;
    for (int r = 0; r <= maxr; ++r) {
        if (t < 64) {
            bool act = (t < 32) && (round_s[t] == r);
            unsigned long long mask = __ballot(act);
            if (act) {
                int pos = __popcll(mask & ((1ull << t) - 1ull));
                list_s[pos] = t;
            }
            if (t == 0) cnt_s = (int)__popcll(mask);
        }
        __syncthreads();
        const int cnt = cnt_s;
        #pragma unroll 1
        for (int pi = w; 2 * pi < cnt; pi += 4) {
            const int sA = list_s[2 * pi];
            const bool doB = (2 * pi + 1 < cnt);
            const int sB = doB ? list_s[2 * pi + 1] : sA;
            const int inA = (prev_s[sA] < 0) ? sA : prev_s[sA];
            const int inB = (prev_s[sB] < 0) ? sB : prev_s[sB];
            const int sX = lowhalf ? sA : sB;
            const int eX = sX >> 1;
            const float ir  = ws[WS_GI + eX * 96 + o];
            const float iz  = ws[WS_GI + eX * 96 + 32 + o];
            const float inn = ws[WS_GI + eX * 96 + 64 + o];
            float acc1 = b1, acc2 = b2, acc3 = b3;
            #pragma unroll
            for (int c = 0; c < 8; ++c) {
                const float4 hs4 = *(const float4*)&slots[inA * 36 + 4 * c];
                const float4 hd4 = *(const float4*)&slots[inB * 36 + 4 * c];
                acc1 += dot4_(w1[c], hs4);
                const float4 hm = lowhalf ? hs4 : hd4;
                acc2 += dot4_(w2[c], hm);
                acc3 += dot4_(w3[c], hd4);
            }
            const float shv = __shfl_xor(lowhalf ? acc3 : acc1, 32);
            const float hr = lowhalf ? acc1 : acc2;
            const float hz = shv;
            const float hn = lowhalf ? acc2 : acc3;
            const float rr = sigmoidf_(ir + hr);
            const float z = sigmoidf_(iz + hz);
            const float nn = tanhf_(inn + rr * hn);
            const float hold = slots[(lowhalf ? inA : inB) * 36 + o];
            const float hnew = (1.f - z) * nn + z * hold;
            if (lowhalf || doB) slots[sX * 36 + o] = hnew;
        }
        __syncthreads();
    }

    // ---- writeback: last occurrence of each node ----
    #pragma unroll
    for (int k = 0; k < 4; ++k) {
        int j2 = j0 + 8 * k;
        if (last_s[j2]) out[16 + nid_s[j2] * 32 + o] = slots[j2 * 36 + o];
    }
}

// ---------------------------------------------------------------------------
extern "C" void kernel_launch(void* const* d_in, const int* in_sizes, int n_in,
                              void* d_out, int out_size, void* d_ws, size_t ws_size,
                              hipStream_t stream)
{
    (void)in_sizes; (void)n_in; (void)out_size; (void)ws_size;
    const int*   src   = (const int*)d_in[0];
    const int*   dst   = (const int*)d_in[1];
    const float* ef    = (const float*)d_in[2];
    const float* nf    = (const float*)d_in[4];
    const float* mem   = (const float*)d_in[6];
    const float* Wemb  = (const float*)d_in[7];
    const float* bemb  = (const float*)d_in[8];
    const float* Wqkv  = (const float*)d_in[9];
    const float* bqkv  = (const float*)d_in[10];
    const float* Wo    = (const float*)d_in[11];
    const float* bo    = (const float*)d_in[12];
    const float* g1    = (const float*)d_in[13];
    const float* be1   = (const float*)d_in[14];
    const float* g2    = (const float*)d_in[15];
    const float* be2   = (const float*)d_in[16];
    const float* Wf1   = (const float*)d_in[17];
    const float* bf1   = (const float*)d_in[18];
    const float* Wf2   = (const float*)d_in[19];
    const float* bf2   = (const float*)d_in[20];
    const float* Wscn  = (const float*)d_in[21];
    const float* bscn  = (const float*)d_in[22];
    const float* gscn  = (const float*)d_in[23];
    const float* bescn = (const float*)d_in[24];
    const float* We1   = (const float*)d_in[25];
    const float* be1e  = (const float*)d_in[26];
    const float* We2   = (const float*)d_in[27];
    const float* be2e  = (const float*)d_in[28];
    const float* We3   = (const float*)d_in[29];
    const float* be3   = (const float*)d_in[30];
    const float* Wih   = (const float*)d_in[31];
    const float* bih   = (const float*)d_in[32];
    const float* Whh   = (const float*)d_in[33];
    const float* bhh   = (const float*)d_in[34];
    const float* Wm1   = (const float*)d_in[35];
    const float* bm1   = (const float*)d_in[36];
    const float* Wm2   = (const float*)d_in[37];
    const float* bm2   = (const float*)d_in[38];
    float* out = (float*)d_out;
    float* ws  = (float*)d_ws;

    hipLaunchKernelGGL(k1_embed_qkv_msg, dim3(256), dim3(256), 0, stream,
        nf, Wemb, bemb, Wqkv, bqkv, mem, src, dst, ef, Wm1, bm1, Wm2, bm2, Wih, bih, ws, out);
    hipLaunchKernelGGL(k2_attn, dim3(128), dim3(256), 0, stream, src, dst, ws);
    hipLaunchKernelGGL(k34_post_scan, dim3(1), dim3(256), 0, stream,
        src, dst, mem, Wo, bo, g1, be1, Wf1, bf1, Wf2, bf2, g2, be2,
        Wscn, bscn, gscn, bescn, Whh, bhh, We1, be1e, We2, be2e, We3, be3, ws, out);
}

// Round 8
// 177.106 us; speedup vs baseline: 1.0052x; 1.0052x over previous
//
#include <hip/hip_runtime.h>
#include <math.h>

#define NN   2048
#define BB   16

// ws layout (float offsets)
#define WS_X0   0
#define WS_QT   65536
#define WS_KT   131072
#define WS_VT   196608
#define WS_GI   268800   // [16 edge][96]
#define WS_SOUT 270336   // [32 slot][16]

__device__ __forceinline__ float sigmoidf_(float x) { return 1.0f / (1.0f + __expf(-x)); }
__device__ __forceinline__ float tanhf_(float x) {
    float ex = __expf(2.0f * x);
    return 1.0f - 2.0f / (ex + 1.0f);
}
__device__ __forceinline__ float dot4_(float4 a, float4 b) {
    return a.x*b.x + a.y*b.y + a.z*b.z + a.w*b.w;
}

// ---------------------------------------------------------------------------
// K1: 256 blocks. All: x0 = nf@Wemb^T+b ; qkv = x0@Wqkv^T+b (head-major).
//     blocks 0..15: message path for edge bx -> gi[bx][96].
//     blocks 16..79: memory -> out[16..] bulk copy.   (unchanged from R7)
// ---------------------------------------------------------------------------
__global__ __launch_bounds__(256) void k1_embed_qkv_msg(
    const float* __restrict__ nf, const float* __restrict__ Wemb, const float* __restrict__ bemb,
    const float* __restrict__ Wqkv, const float* __restrict__ bqkv,
    const float* __restrict__ mem, const int* __restrict__ src, const int* __restrict__ dst,
    const float* __restrict__ ef,
    const float* __restrict__ Wm1, const float* __restrict__ bm1,
    const float* __restrict__ Wm2, const float* __restrict__ bm2,
    const float* __restrict__ Wih, const float* __restrict__ bih,
    float* __restrict__ ws, float* __restrict__ out)
{
    __shared__ float We_s[32 * 130];
    __shared__ float nf_s[8 * 130];
    __shared__ float x0_s[8 * 33];
    __shared__ float Wq_s[96 * 33];
    __shared__ __align__(16) float Wm1_s[2144];
    __shared__ float Wm2_s[32 * 33];
    __shared__ float Wih_s[96 * 33];
    __shared__ float min_s[67];
    __shared__ float mr_s[32];
    __shared__ float msg_s[32];

    const int t = threadIdx.x, bx = blockIdx.x;
    const bool domsg = (bx < 16);

    float4 rA[4], rB[3], rC;
    #pragma unroll
    for (int k = 0; k < 4; ++k) rA[k] = ((const float4*)Wemb)[t + 256 * k];
    #pragma unroll
    for (int k = 0; k < 3; ++k) rB[k] = ((const float4*)Wqkv)[t + 256 * k];
    rC = ((const float4*)nf)[bx * 256 + t];

    float4 rm1[3], rm2v, rih[3];
    float rminv = 0.f;
    if (domsg) {
        #pragma unroll
        for (int k = 0; k < 3; ++k) {
            int idx = t + 256 * k;
            rm1[k] = (idx < 536) ? ((const float4*)Wm1)[idx] : make_float4(0,0,0,0);
        }
        rm2v = ((const float4*)Wm2)[t];
        #pragma unroll
        for (int k = 0; k < 3; ++k) rih[k] = ((const float4*)Wih)[t + 256 * k];
        if (t < 67) {
            const int e = bx;
            rminv = (t < 32) ? mem[src[e] * 32 + t]
                  : (t < 64) ? mem[dst[e] * 32 + (t - 32)]
                             : ef[e * 3 + (t - 64)];
        }
    }

    if (bx >= 16 && bx < 80) {
        int g = (bx - 16) * 256 + t;
        ((float4*)(out + 16))[g] = ((const float4*)mem)[g];
    }

    #pragma unroll
    for (int k = 0; k < 4; ++k) {
        int idx = t + 256 * k;
        int r = idx >> 5, c = (idx & 31) * 4;
        We_s[r * 130 + c] = rA[k].x; We_s[r * 130 + c + 1] = rA[k].y;
        We_s[r * 130 + c + 2] = rA[k].z; We_s[r * 130 + c + 3] = rA[k].w;
    }
    #pragma unroll
    for (int k = 0; k < 3; ++k) {
        int idx = t + 256 * k;
        int r = idx >> 3, c = (idx & 7) * 4;
        Wq_s[r * 33 + c] = rB[k].x; Wq_s[r * 33 + c + 1] = rB[k].y;
        Wq_s[r * 33 + c + 2] = rB[k].z; Wq_s[r * 33 + c + 3] = rB[k].w;
    }
    {
        int r = t >> 5, c = (t & 31) * 4;
        nf_s[r * 130 + c] = rC.x; nf_s[r * 130 + c + 1] = rC.y;
        nf_s[r * 130 + c + 2] = rC.z; nf_s[r * 130 + c + 3] = rC.w;
    }
    if (domsg) {
        #pragma unroll
        for (int k = 0; k < 3; ++k) {
            int idx = t + 256 * k;
            if (idx < 536) ((float4*)Wm1_s)[idx] = rm1[k];
        }
        { int r = t >> 3, c = (t & 7) * 4;
          Wm2_s[r * 33 + c] = rm2v.x; Wm2_s[r * 33 + c + 1] = rm2v.y;
          Wm2_s[r * 33 + c + 2] = rm2v.z; Wm2_s[r * 33 + c + 3] = rm2v.w; }
        #pragma unroll
        for (int k = 0; k < 3; ++k) {
            int idx = t + 256 * k;
            int r = idx >> 3, c = (idx & 7) * 4;
            Wih_s[r * 33 + c] = rih[k].x; Wih_s[r * 33 + c + 1] = rih[k].y;
            Wih_s[r * 33 + c + 2] = rih[k].z; Wih_s[r * 33 + c + 3] = rih[k].w;
        }
        if (t < 67) min_s[t] = rminv;
    }
    __syncthreads();

    const int j = t >> 5, o = t & 31;
    const int n = bx * 8 + j;

    float acc = bemb[o];
    {
        const float2* Wr = (const float2*)&We_s[o * 130];
        const float2* Nr = (const float2*)&nf_s[j * 130];
        float sx = 0.f, sy = 0.f;
        #pragma unroll 16
        for (int i = 0; i < 64; ++i) {
            float2 w = Wr[i], x = Nr[i];
            sx += w.x * x.x; sy += w.y * x.y;
        }
        acc += sx + sy;
    }
    x0_s[j * 33 + o] = acc;
    ws[WS_X0 + n * 32 + o] = acc;
    if (domsg && t < 32) {
        float a1 = bm1[t];
        for (int i = 0; i < 67; ++i) a1 += Wm1_s[t * 67 + i] * min_s[i];
        mr_s[t] = fmaxf(a1, 0.f);
    }
    __syncthreads();

    #pragma unroll
    for (int c = 0; c < 3; ++c) {
        int oo = c * 32 + o;
        float a2 = bqkv[oo];
        #pragma unroll 8
        for (int i = 0; i < 32; ++i) a2 += Wq_s[oo * 33 + i] * x0_s[j * 33 + i];
        int h = o >> 3, d = o & 7;
        float* base = ws + (c == 0 ? WS_QT : (c == 1 ? WS_KT : WS_VT));
        base[h * 16384 + n * 8 + d] = a2;  // [h][n][d]
    }
    if (domsg && t < 32) {
        float a2 = bm2[t];
        #pragma unroll 8
        for (int i = 0; i < 32; ++i) a2 += Wm2_s[t * 33 + i] * mr_s[i];
        msg_s[t] = a2;
    }
    __syncthreads();

    if (domsg && t < 96) {
        float a3 = bih[t];
        #pragma unroll 8
        for (int i = 0; i < 32; ++i) a3 += Wih_s[t * 33 + i] * msg_s[i];
        ws[WS_GI + bx * 96 + t] = a3;  // [e][96]
    }
}

// ---------------------------------------------------------------------------
// K2': 32 blocks (one per slot). 4 waves = 4 heads; each wave scans all 2048
// keys (no cross-block partials). Then wave 0 runs the whole per-slot post
// path (Wo->LN1->FFN->LN2->SCN-LN-relu) BARRIER-FREE (single-wave in-order
// LDS), with all weights/biases preloaded into registers at entry so the
// load latency hides under the attention phase. Writes sout[slot][16].
// ---------------------------------------------------------------------------
__global__ __launch_bounds__(256, 1) void k2_attn_post(
    const int* __restrict__ src, const int* __restrict__ dst,
    const float* __restrict__ Wo, const float* __restrict__ bo,
    const float* __restrict__ g1, const float* __restrict__ be1,
    const float* __restrict__ Wf1, const float* __restrict__ bf1,
    const float* __restrict__ Wf2, const float* __restrict__ bf2,
    const float* __restrict__ g2, const float* __restrict__ be2,
    const float* __restrict__ Wscn, const float* __restrict__ bscn,
    const float* __restrict__ gscn, const float* __restrict__ bescn,
    float* __restrict__ ws)
{
    __shared__ float arow_s[32];
    __shared__ float x1_s[32];
    __shared__ float fs_s[64];
    __shared__ float x2_s[32];

    const int t = threadIdx.x, s = blockIdx.x;
    const int h = t >> 6, l = t & 63;
    const int e = s >> 1;
    const int n = (s & 1) ? dst[e] : src[e];

    // ---- entry: preload post weights/biases into regs (latency hides) ----
    float4 wo_r[8], wf2_r[16], wf1_r[8], wscn_r[8];
    float x0v = 0.f, bo_v = 0.f, g1_v = 0.f, be1_v = 0.f, bf2_v = 0.f;
    float g2_v = 0.f, be2_v = 0.f, bf1_v = 0.f, bscn_v = 0.f, gscn_v = 0.f, bescn_v = 0.f;
    if (t < 32) {
        #pragma unroll
        for (int c = 0; c < 8; ++c)  wo_r[c]  = ((const float4*)(Wo  + t * 32))[c];
        #pragma unroll
        for (int c = 0; c < 16; ++c) wf2_r[c] = ((const float4*)(Wf2 + t * 64))[c];
        x0v = ws[WS_X0 + n * 32 + t];
        bo_v = bo[t]; g1_v = g1[t]; be1_v = be1[t];
        bf2_v = bf2[t]; g2_v = g2[t]; be2_v = be2[t];
    }
    if (t < 64) {
        #pragma unroll
        for (int c = 0; c < 8; ++c) wf1_r[c] = ((const float4*)(Wf1 + t * 32))[c];
        bf1_v = bf1[t];
    }
    if (t < 16) {
        #pragma unroll
        for (int c = 0; c < 8; ++c) wscn_r[c] = ((const float4*)(Wscn + t * 32))[c];
        bscn_v = bscn[t]; gscn_v = gscn[t]; bescn_v = bescn[t];
    }

    // ---- attention: wave h over all 2048 keys ----
    const float* qg = ws + WS_QT + h * 16384 + n * 8;
    const float4 qa  = *(const float4*)qg;
    const float4 qb4 = *(const float4*)(qg + 4);
    const float* kbase = ws + WS_KT + h * 16384;
    const float* vbase = ws + WS_VT + h * 16384;

    float4 oa = make_float4(0.f, 0.f, 0.f, 0.f);
    float4 ob = make_float4(0.f, 0.f, 0.f, 0.f);
    float ssum = 0.f;
    const float scale = 0.35355339059327373f;  // 1/sqrt(8)

    #pragma unroll 4
    for (int i = 0; i < 32; ++i) {
        const int key = i * 64 + l;
        const float4 ka = *(const float4*)(kbase + key * 8);
        const float4 kb = *(const float4*)(kbase + key * 8 + 4);
        const float sc = (dot4_(qa, ka) + dot4_(qb4, kb)) * scale;
        const float p = __expf(sc);
        ssum += p;
        const float4 va = *(const float4*)(vbase + key * 8);
        const float4 vb = *(const float4*)(vbase + key * 8 + 4);
        oa.x += p * va.x; oa.y += p * va.y; oa.z += p * va.z; oa.w += p * va.w;
        ob.x += p * vb.x; ob.y += p * vb.y; ob.z += p * vb.z; ob.w += p * vb.w;
    }
    #pragma unroll
    for (int m = 1; m <= 32; m <<= 1) {
        ssum += __shfl_xor(ssum, m);
        oa.x += __shfl_xor(oa.x, m); oa.y += __shfl_xor(oa.y, m);
        oa.z += __shfl_xor(oa.z, m); oa.w += __shfl_xor(oa.w, m);
        ob.x += __shfl_xor(ob.x, m); ob.y += __shfl_xor(ob.y, m);
        ob.z += __shfl_xor(ob.z, m); ob.w += __shfl_xor(ob.w, m);
    }
    if (l == 0) {
        const float inv = 1.0f / ssum;
        float* ap = arow_s + h * 8;
        ap[0] = oa.x * inv; ap[1] = oa.y * inv; ap[2] = oa.z * inv; ap[3] = oa.w * inv;
        ap[4] = ob.x * inv; ap[5] = ob.y * inv; ap[6] = ob.z * inv; ap[7] = ob.w * inv;
    }
    __syncthreads();

    // ---- post path: wave 0 only, barrier-free (in-order LDS within wave) ----
    if (t < 64) {
        float x1 = 0.f;
        if (t < 32) {
            float a = bo_v;
            #pragma unroll
            for (int c = 0; c < 8; ++c) {
                a = fmaf(wo_r[c].x, arow_s[4 * c],     a);
                a = fmaf(wo_r[c].y, arow_s[4 * c + 1], a);
                a = fmaf(wo_r[c].z, arow_s[4 * c + 2], a);
                a = fmaf(wo_r[c].w, arow_s[4 * c + 3], a);
            }
            const float t1 = x0v + a;
            float mu = t1;
            #pragma unroll
            for (int m = 16; m >= 1; m >>= 1) mu += __shfl_xor(mu, m, 32);
            mu *= (1.f / 32.f);
            const float dv = t1 - mu;
            float var = dv * dv;
            #pragma unroll
            for (int m = 16; m >= 1; m >>= 1) var += __shfl_xor(var, m, 32);
            var *= (1.f / 32.f);
            x1 = dv * rsqrtf(var + 1e-5f) * g1_v + be1_v;
            x1_s[t] = x1;
        }
        // FFN1 + gelu (64 lanes)
        {
            float f = bf1_v;
            #pragma unroll
            for (int c = 0; c < 8; ++c) {
                f = fmaf(wf1_r[c].x, x1_s[4 * c],     f);
                f = fmaf(wf1_r[c].y, x1_s[4 * c + 1], f);
                f = fmaf(wf1_r[c].z, x1_s[4 * c + 2], f);
                f = fmaf(wf1_r[c].w, x1_s[4 * c + 3], f);
            }
            fs_s[t] = 0.5f * f * (1.f + erff(f * 0.70710678118654752f));
        }
        // FFN2 + residual + LN2 (32 lanes)
        if (t < 32) {
            float f2 = bf2_v;
            #pragma unroll
            for (int c = 0; c < 16; ++c) {
                f2 = fmaf(wf2_r[c].x, fs_s[4 * c],     f2);
                f2 = fmaf(wf2_r[c].y, fs_s[4 * c + 1], f2);
                f2 = fmaf(wf2_r[c].z, fs_s[4 * c + 2], f2);
                f2 = fmaf(wf2_r[c].w, fs_s[4 * c + 3], f2);
            }
            const float t2 = x1 + f2;
            float mu2 = t2;
            #pragma unroll
            for (int m = 16; m >= 1; m >>= 1) mu2 += __shfl_xor(mu2, m, 32);
            mu2 *= (1.f / 32.f);
            const float dv2 = t2 - mu2;
            float var2 = dv2 * dv2;
            #pragma unroll
            for (int m = 16; m >= 1; m >>= 1) var2 += __shfl_xor(var2, m, 32);
            var2 *= (1.f / 32.f);
            x2_s[t] = dv2 * rsqrtf(var2 + 1e-5f) * g2_v + be2_v;
        }
        // SCN + LN(16) + relu (16 lanes) -> sout
        if (t < 16) {
            float sc = bscn_v;
            #pragma unroll
            for (int c = 0; c < 8; ++c) {
                sc = fmaf(wscn_r[c].x, x2_s[4 * c],     sc);
                sc = fmaf(wscn_r[c].y, x2_s[4 * c + 1], sc);
                sc = fmaf(wscn_r[c].z, x2_s[4 * c + 2], sc);
                sc = fmaf(wscn_r[c].w, x2_s[4 * c + 3], sc);
            }
            float m16 = sc;
            #pragma unroll
            for (int m = 8; m >= 1; m >>= 1) m16 += __shfl_xor(m16, m, 16);
            m16 *= (1.f / 16.f);
            const float d16 = sc - m16;
            float v16 = d16 * d16;
            #pragma unroll
            for (int m = 8; m >= 1; m >>= 1) v16 += __shfl_xor(v16, m, 16);
            v16 *= (1.f / 16.f);
            const float sv = d16 * rsqrtf(v16 + 1e-5f) * gscn_v + bescn_v;
            ws[WS_SOUT + s * 16 + t] = fmaxf(sv, 0.f);
        }
    }
}

// ---------------------------------------------------------------------------
// K3': the minimal serial remainder: edge-head MLP -> logits; round-parallel
// GRU scan; writeback. One block, 256 threads. Small code footprint.
// ---------------------------------------------------------------------------
__global__ __launch_bounds__(256, 1) void k3_edge_scan(
    const int* __restrict__ src, const int* __restrict__ dst,
    const float* __restrict__ mem,
    const float* __restrict__ Whh, const float* __restrict__ bhh,
    const float* __restrict__ We1, const float* __restrict__ be1e,
    const float* __restrict__ We2, const float* __restrict__ be2e,
    const float* __restrict__ We3, const float* __restrict__ be3,
    float* __restrict__ ws, float* __restrict__ out)
{
    __shared__ float cat_s[16 * 33];
    __shared__ float h1_s[16 * 33];
    __shared__ float h2_s[16 * 17];
    __shared__ __align__(16) float slots[32 * 36];
    __shared__ int nid_s[32], prev_s[32], round_s[32], last_s[32];
    __shared__ int list_s[32], cnt_s, maxr_s;

    const int t = threadIdx.x;
    const int j0 = t >> 5, o = t & 31;
    const int l = t & 63, w = t >> 6;
    const bool lowhalf = (l < 32);

    // ---- entry: GRU + edge-head weights into regs ----
    float4 w1[8], w2[8], w3[8];
    const int r2 = lowhalf ? l + 64 : l - 32;
    const int r3 = l + 32;
    #pragma unroll
    for (int c = 0; c < 8; ++c) {
        w1[c] = ((const float4*)Whh)[l * 8 + c];
        w2[c] = ((const float4*)Whh)[r2 * 8 + c];
        w3[c] = ((const float4*)Whh)[r3 * 8 + c];
    }
    const float b1 = bhh[l], b2 = bhh[r2], b3 = bhh[r3];

    float4 we1_r[8], we2_r[8];
    #pragma unroll
    for (int c = 0; c < 8; ++c) {
        we1_r[c] = ((const float4*)(We1 + o * 32))[c];
        we2_r[c] = ((const float4*)(We2 + (t & 15) * 32))[c];
    }
    const float be1e_v = be1e[o];

    if (t < 32) nid_s[t] = (t & 1) ? dst[t >> 1] : src[t >> 1];

    // stage cat (sout pairs) from ws
    #pragma unroll
    for (int k = 0; k < 2; ++k) {
        const int idx = t + 256 * k;
        const int e = idx >> 5, i = idx & 31;
        cat_s[e * 33 + i] = (i < 16) ? ws[WS_SOUT + (2 * e) * 16 + i]
                                     : ws[WS_SOUT + (2 * e + 1) * 16 + (i - 16)];
    }
    __syncthreads();

    // bookkeeping (t<32); slots init (all); h1 (all)
    if (t < 32) {
        const int me = nid_s[t];
        int pv = -1, rd = 0;
        for (int j2 = 0; j2 < t; ++j2) if (nid_s[j2] == me) { pv = j2; ++rd; }
        prev_s[t] = pv; round_s[t] = rd;
        int isl = 1;
        for (int j2 = t + 1; j2 < 32; ++j2) if (nid_s[j2] == me) { isl = 0; break; }
        last_s[t] = isl;
        int mr = rd;
        #pragma unroll
        for (int m = 16; m >= 1; m >>= 1) mr = max(mr, __shfl_xor(mr, m, 32));
        if (t == 0) maxr_s = mr;
    }
    #pragma unroll
    for (int k = 0; k < 4; ++k) {
        const int j2 = j0 + 8 * k;
        slots[j2 * 36 + o] = mem[nid_s[j2] * 32 + o];
    }
    #pragma unroll 1
    for (int k = 0; k < 2; ++k) {
        const int e = j0 + 8 * k;
        float acc = be1e_v;
        #pragma unroll
        for (int c = 0; c < 8; ++c) {
            acc = fmaf(we1_r[c].x, cat_s[e * 33 + 4 * c],     acc);
            acc = fmaf(we1_r[c].y, cat_s[e * 33 + 4 * c + 1], acc);
            acc = fmaf(we1_r[c].z, cat_s[e * 33 + 4 * c + 2], acc);
            acc = fmaf(we1_r[c].w, cat_s[e * 33 + 4 * c + 3], acc);
        }
        h1_s[e * 33 + o] = fmaxf(acc, 0.f);
    }
    __syncthreads();

    // h2 (16 edges x 16 outs over 256 threads)
    {
        const int e = t >> 4, o2 = t & 15;
        float acc = be2e[o2];
        #pragma unroll
        for (int c = 0; c < 8; ++c) {
            acc = fmaf(we2_r[c].x, h1_s[e * 33 + 4 * c],     acc);
            acc = fmaf(we2_r[c].y, h1_s[e * 33 + 4 * c + 1], acc);
            acc = fmaf(we2_r[c].z, h1_s[e * 33 + 4 * c + 2], acc);
            acc = fmaf(we2_r[c].w, h1_s[e * 33 + 4 * c + 3], acc);
        }
        h2_s[e * 17 + o2] = fmaxf(acc, 0.f);
    }
    __syncthreads();

    // logits
    if (t < 16) {
        float acc = be3[0];
        #pragma unroll
        for (int i = 0; i < 16; ++i) acc = fmaf(We3[i], h2_s[t * 17 + i], acc);
        out[t] = acc;
    }

    // ---- round-parallel GRU scan (4 waves x 2 slots/pass) ----
    const int maxr = maxr_s;
    for (int r = 0; r <= maxr; ++r) {
        if (t < 64) {
            const bool act = (t < 32) && (round_s[t] == r);
            const unsigned long long mask = __ballot(act);
            if (act) {
                const int pos = __popcll(mask & ((1ull << t) - 1ull));
                list_s[pos] = t;
            }
            if (t == 0) cnt_s = (int)__popcll(mask);
        }
        __syncthreads();
        const int cnt = cnt_s;
        #pragma unroll 1
        for (int pi = w; 2 * pi < cnt; pi += 4) {
            const int sA = list_s[2 * pi];
            const bool doB = (2 * pi + 1 < cnt);
            const int sB = doB ? list_s[2 * pi + 1] : sA;
            const int inA = (prev_s[sA] < 0) ? sA : prev_s[sA];
            const int inB = (prev_s[sB] < 0) ? sB : prev_s[sB];
            const int sX = lowhalf ? sA : sB;
            const int eX = sX >> 1;
            const float ir  = ws[WS_GI + eX * 96 + o];
            const float iz  = ws[WS_GI + eX * 96 + 32 + o];
            const float inn = ws[WS_GI + eX * 96 + 64 + o];
            float acc1 = b1, acc2 = b2, acc3 = b3;
            #pragma unroll
            for (int c = 0; c < 8; ++c) {
                const float4 hs4 = *(const float4*)&slots[inA * 36 + 4 * c];
                const float4 hd4 = *(const float4*)&slots[inB * 36 + 4 * c];
                acc1 += dot4_(w1[c], hs4);
                const float4 hm = lowhalf ? hs4 : hd4;
                acc2 += dot4_(w2[c], hm);
                acc3 += dot4_(w3[c], hd4);
            }
            const float shv = __shfl_xor(lowhalf ? acc3 : acc1, 32);
            const float hr = lowhalf ? acc1 : acc2;
            const float hz = shv;
            const float hn = lowhalf ? acc2 : acc3;
            const float rr = sigmoidf_(ir + hr);
            const float z = sigmoidf_(iz + hz);
            const float nn = tanhf_(inn + rr * hn);
            const float hold = slots[(lowhalf ? inA : inB) * 36 + o];
            const float hnew = (1.f - z) * nn + z * hold;
            if (lowhalf || doB) slots[sX * 36 + o] = hnew;
        }
        __syncthreads();
    }

    // ---- writeback: last occurrence of each node ----
    #pragma unroll
    for (int k = 0; k < 4; ++k) {
        const int j2 = j0 + 8 * k;
        if (last_s[j2]) out[16 + nid_s[j2] * 32 + o] = slots[j2 * 36 + o];
    }
}

// ---------------------------------------------------------------------------
extern "C" void kernel_launch(void* const* d_in, const int* in_sizes, int n_in,
                              void* d_out, int out_size, void* d_ws, size_t ws_size,
                              hipStream_t stream)
{
    (void)in_sizes; (void)n_in; (void)out_size; (void)ws_size;
    const int*   src   = (const int*)d_in[0];
    const int*   dst   = (const int*)d_in[1];
    const float* ef    = (const float*)d_in[2];
    const float* nf    = (const float*)d_in[4];
    const float* mem   = (const float*)d_in[6];
    const float* Wemb  = (const float*)d_in[7];
    const float* bemb  = (const float*)d_in[8];
    const float* Wqkv  = (const float*)d_in[9];
    const float* bqkv  = (const float*)d_in[10];
    const float* Wo    = (const float*)d_in[11];
    const float* bo    = (const float*)d_in[12];
    const float* g1    = (const float*)d_in[13];
    const float* be1   = (const float*)d_in[14];
    const float* g2    = (const float*)d_in[15];
    const float* be2   = (const float*)d_in[16];
    const float* Wf1   = (const float*)d_in[17];
    const float* bf1   = (const float*)d_in[18];
    const float* Wf2   = (const float*)d_in[19];
    const float* bf2   = (const float*)d_in[20];
    const float* Wscn  = (const float*)d_in[21];
    const float* bscn  = (const float*)d_in[22];
    const float* gscn  = (const float*)d_in[23];
    const float* bescn = (const float*)d_in[24];
    const float* We1   = (const float*)d_in[25];
    const float* be1e  = (const float*)d_in[26];
    const float* We2   = (const float*)d_in[27];
    const float* be2e  = (const float*)d_in[28];
    const float* We3   = (const float*)d_in[29];
    const float* be3   = (const float*)d_in[30];
    const float* Wih   = (const float*)d_in[31];
    const float* bih   = (const float*)d_in[32];
    const float* Whh   = (const float*)d_in[33];
    const float* bhh   = (const float*)d_in[34];
    const float* Wm1   = (const float*)d_in[35];
    const float* bm1   = (const float*)d_in[36];
    const float* Wm2   = (const float*)d_in[37];
    const float* bm2   = (const float*)d_in[38];
    float* out = (float*)d_out;
    float* ws  = (float*)d_ws;

    hipLaunchKernelGGL(k1_embed_qkv_msg, dim3(256), dim3(256), 0, stream,
        nf, Wemb, bemb, Wqkv, bqkv, mem, src, dst, ef, Wm1, bm1, Wm2, bm2, Wih, bih, ws, out);
    hipLaunchKernelGGL(k2_attn_post, dim3(32), dim3(256), 0, stream,
        src, dst, Wo, bo, g1, be1, Wf1, bf1, Wf2, bf2, g2, be2,
        Wscn, bscn, gscn, bescn, ws);
    hipLaunchKernelGGL(k3_edge_scan, dim3(1), dim3(256), 0, stream,
        src, dst, mem, Whh, bhh, We1, be1e, We2, be2e, We3, be3, ws, out);
}